// Round 3
// baseline (60.496 us; speedup 1.0000x reference)
//
#include <hip/hip_runtime.h>
#include <hip/hip_bf16.h>

// Chamfer loss via MFMA, B=16, N=4096, D=3, fp32 in/out.
// d2[p][q] = ||p||^2 + ||q||^2 - 2 p.q computed as a 32x32 MFMA tile:
//   A row (K=16, f16 hi/lo split): {pnh, pnl, axh, ayh, azh, axl, ayl, azl,
//                                   axh, ayh, azh, 0,0,0,0,0}   (a = -2p)
//   B col:                         {1,   1,   qxh, qyh, qzh, qxh, qyh, qzh,
//                                   qxl, qyl, qzl, 0,0,0,0,0}
//   -> D = pn + a.q  (error ~1e-4; ||q||^2 added per-column after the min)
// min over rows accumulates per lane (col = lane&31); both directions are
// separate kernel instances combined by uint atomicMin on >=0 floats.

typedef _Float16 half8   __attribute__((ext_vector_type(8)));
typedef float    floatx16 __attribute__((ext_vector_type(16)));

#define CH_B 16
#define CH_N 4096
#define CH_BLOCK 256
#define CH_QT 256                        // q-cols per block (64/wave)
#define CH_NQT (CH_N / CH_QT)            // 16
#define CH_PSPLIT 2
#define CH_PSLICE (CH_N / CH_PSPLIT)     // 2048
#define CH_CHUNK 256                     // staged p-rows per chunk
#define CH_NCHUNK (CH_PSLICE / CH_CHUNK) // 8
#define CH_TILES (CH_CHUNK / 32)         // 8 MFMA row-tiles per chunk

__global__ __launch_bounds__(CH_BLOCK) void chamfer_mfma(
    const float* __restrict__ src,
    const float* __restrict__ trg,
    unsigned int* __restrict__ out_all)
{
    // tile t, kgroup kg (k 0..7 / 8..15), row r -> frag index t*64 + kg*32 + r
    __shared__ half8 lds[2][CH_TILES * 64];  // 2 x 8KB

    const int tid  = threadIdx.x;
    const int lane = tid & 63;
    const int wave = tid >> 6;
    const int l31  = lane & 31;
    const int lhi  = lane >> 5;

    const int bz  = blockIdx.z;
    const int b   = bz & (CH_B - 1);
    const int dir = bz >> 4;             // 0: rows=src, cols=trg ; 1: swapped
    const float* P = dir ? trg : src;
    const float* Q = dir ? src : trg;
    unsigned int* out = out_all + ((size_t)dir * CH_B + b) * CH_N;

    const float* Pb = P + ((size_t)b * CH_N + (size_t)blockIdx.y * CH_PSLICE) * 3;
    const float* Qb = Q + (size_t)b * CH_N * 3;

    // ---- B fragments: 2 sets of 32 cols, built once into registers ----
    half8 bfrag[2];
    float qn[2];
    const int col0 = blockIdx.x * CH_QT + wave * 64 + l31;
    #pragma unroll
    for (int s = 0; s < 2; ++s) {
        const int col = col0 + s * 32;
        const float qx = Qb[col * 3 + 0], qy = Qb[col * 3 + 1], qz = Qb[col * 3 + 2];
        qn[s] = qx * qx + qy * qy + qz * qz;
        const _Float16 xh = (_Float16)qx, yh = (_Float16)qy, zh = (_Float16)qz;
        const _Float16 xl = (_Float16)(qx - (float)xh);
        const _Float16 yl = (_Float16)(qy - (float)yh);
        const _Float16 zl = (_Float16)(qz - (float)zh);
        half8 f;
        if (lhi == 0) {      // k = 0..7
            f[0] = (_Float16)1.0f; f[1] = (_Float16)1.0f;
            f[2] = xh; f[3] = yh; f[4] = zh;
            f[5] = xh; f[6] = yh; f[7] = zh;
        } else {             // k = 8..15
            f[0] = xl; f[1] = yl; f[2] = zl;
            f[3] = (_Float16)0.0f; f[4] = (_Float16)0.0f;
            f[5] = (_Float16)0.0f; f[6] = (_Float16)0.0f; f[7] = (_Float16)0.0f;
        }
        bfrag[s] = f;
    }

    // ---- staging: one p-row per thread, f16 hi/lo A-frag layout ----
    auto stage = [&](int buf, float px, float py, float pz) {
        const float ax = -2.0f * px, ay = -2.0f * py, az = -2.0f * pz;
        const float pn = px * px + py * py + pz * pz;
        const _Float16 axh = (_Float16)ax, ayh = (_Float16)ay, azh = (_Float16)az;
        const _Float16 axl = (_Float16)(ax - (float)axh);
        const _Float16 ayl = (_Float16)(ay - (float)ayh);
        const _Float16 azl = (_Float16)(az - (float)azh);
        const _Float16 pnh = (_Float16)pn;
        const _Float16 pnl = (_Float16)(pn - (float)pnh);
        const _Float16 z0 = (_Float16)0.0f;
        half8 k0 = {pnh, pnl, axh, ayh, azh, axl, ayl, azl};   // k 0..7
        half8 k1 = {axh, ayh, azh, z0, z0, z0, z0, z0};        // k 8..15
        const int t = tid >> 5, rr = tid & 31;
        lds[buf][t * 64 + rr]      = k0;
        lds[buf][t * 64 + 32 + rr] = k1;
    };

    float px = Pb[tid * 3 + 0], py = Pb[tid * 3 + 1], pz = Pb[tid * 3 + 2];
    stage(0, px, py, pz);
    __syncthreads();

    const floatx16 zero = {0.f,0.f,0.f,0.f,0.f,0.f,0.f,0.f,
                           0.f,0.f,0.f,0.f,0.f,0.f,0.f,0.f};
    float m0 = __builtin_inff(), m1 = __builtin_inff();
    const int ridx = lhi * 32 + l31;   // == lane: conflict-free ds_read_b128

    for (int c = 0; c < CH_NCHUNK; ++c) {
        const int cur = c & 1;
        const bool more = (c + 1 < CH_NCHUNK);
        float nx = 0.f, ny = 0.f, nz = 0.f;
        if (more) {   // issue next-chunk loads early; latency hides under MFMA
            const float* r = Pb + ((size_t)(c + 1) * CH_CHUNK + tid) * 3;
            nx = r[0]; ny = r[1]; nz = r[2];
        }
        const half8* buf = lds[cur];
        #pragma unroll
        for (int t = 0; t < CH_TILES; ++t) {
            const half8 a = buf[t * 64 + ridx];
            floatx16 d0 = __builtin_amdgcn_mfma_f32_32x32x16_f16(a, bfrag[0], zero, 0, 0, 0);
            floatx16 d1 = __builtin_amdgcn_mfma_f32_32x32x16_f16(a, bfrag[1], zero, 0, 0, 0);
            float u0 = fminf(fminf(d0[0], d0[1]), d0[2]);
            u0 = fminf(fminf(u0, d0[3]),  d0[4]);
            u0 = fminf(fminf(u0, d0[5]),  d0[6]);
            u0 = fminf(fminf(u0, d0[7]),  d0[8]);
            u0 = fminf(fminf(u0, d0[9]),  d0[10]);
            u0 = fminf(fminf(u0, d0[11]), d0[12]);
            u0 = fminf(fminf(u0, d0[13]), d0[14]);
            m0 = fminf(fminf(m0, u0), d0[15]);
            float u1 = fminf(fminf(d1[0], d1[1]), d1[2]);
            u1 = fminf(fminf(u1, d1[3]),  d1[4]);
            u1 = fminf(fminf(u1, d1[5]),  d1[6]);
            u1 = fminf(fminf(u1, d1[7]),  d1[8]);
            u1 = fminf(fminf(u1, d1[9]),  d1[10]);
            u1 = fminf(fminf(u1, d1[11]), d1[12]);
            m1 = fminf(fminf(m1, u1), d1[15]);
            m1 = fminf(m1, d1[13]);
            m1 = fminf(m1, d1[14]);
        }
        if (more) stage(cur ^ 1, nx, ny, nz);
        __syncthreads();
    }

    // epilogue: add ||q||^2, clamp, combine lane halves, global atomicMin
    float v0 = fmaxf(m0 + qn[0], 0.0f);
    float v1 = fmaxf(m1 + qn[1], 0.0f);
    v0 = fminf(v0, __shfl_xor(v0, 32));
    v1 = fminf(v1, __shfl_xor(v1, 32));
    if (lane < 32) {
        atomicMin(&out[col0],      __float_as_uint(v0));
        atomicMin(&out[col0 + 32], __float_as_uint(v1));
    }
}

extern "C" void kernel_launch(void* const* d_in, const int* in_sizes, int n_in,
                              void* d_out, int out_size, void* d_ws, size_t ws_size,
                              hipStream_t stream) {
    const float* src = (const float*)d_in[0];
    const float* trg = (const float*)d_in[1];
    unsigned int* out = (unsigned int*)d_out;

    // Init outputs to 0x7f7f7f7f (~3.4e38): valid +inf under uint-ordered min
    // for nonnegative values.
    hipMemsetAsync(out, 0x7f, (size_t)2 * CH_B * CH_N * sizeof(float), stream);

    dim3 grid(CH_NQT, CH_PSPLIT, 2 * CH_B);
    chamfer_mfma<<<grid, dim3(CH_BLOCK), 0, stream>>>(src, trg, out);
}

// Round 4
// 34.982 us; speedup vs baseline: 1.7293x; 1.7293x over previous
//
#include <hip/hip_runtime.h>
#include <hip/hip_bf16.h>

// Chamfer loss via MFMA, B=16, N=4096, D=3, fp32 in/out.
// d2[p][q] = ||p||^2 + ||q||^2 - 2 p.q as a 32x32x16 f16 MFMA tile with
// hi/lo f16 split (error ~1e-3; ||q||^2 added per-column after the min).
// A-fragments precomputed into d_ws by build_afrag (no LDS / barriers in the
// main kernel); both directions combined by uint atomicMin on >=0 floats.

typedef _Float16 half8    __attribute__((ext_vector_type(8)));
typedef float    floatx16 __attribute__((ext_vector_type(16)));

#define CH_B 16
#define CH_N 4096
#define CH_BLOCK 256
#define CH_QT 256                          // q-cols per block (64/wave)
#define CH_NQT (CH_N / CH_QT)              // 16
#define CH_PSPLIT 2
#define CH_TILES_TOTAL (CH_N / 32)         // 128 row-tiles per (dir,b)
#define CH_TILES_BLK (CH_TILES_TOTAL / CH_PSPLIT)  // 64 per block

// One thread per point (dir,b,r): build the K=16 hi/lo A-fragment.
__global__ __launch_bounds__(CH_BLOCK) void build_afrag(
    const float* __restrict__ src, const float* __restrict__ trg,
    half8* __restrict__ af)
{
    const int gid = blockIdx.x * CH_BLOCK + threadIdx.x;  // 0 .. 2*16*4096
    const int r   = gid & (CH_N - 1);
    const int bb  = gid >> 12;            // dir*16 + b
    const int dir = bb >> 4;
    const float* P = dir ? trg : src;
    const float* p = P + ((size_t)(bb & 15) * CH_N + r) * 3;
    const float px = p[0], py = p[1], pz = p[2];
    const float ax = -2.0f * px, ay = -2.0f * py, az = -2.0f * pz;
    const float pn = px * px + py * py + pz * pz;
    const _Float16 axh = (_Float16)ax, ayh = (_Float16)ay, azh = (_Float16)az;
    const _Float16 axl = (_Float16)(ax - (float)axh);
    const _Float16 ayl = (_Float16)(ay - (float)ayh);
    const _Float16 azl = (_Float16)(az - (float)azh);
    const _Float16 pnh = (_Float16)pn, pnl = (_Float16)(pn - (float)pnh);
    const _Float16 z0 = (_Float16)0.0f;
    half8 k0 = {pnh, pnl, axh, ayh, azh, axl, ayl, azl};  // k 0..7
    half8 k1 = {axh, ayh, azh, z0, z0, z0, z0, z0};       // k 8..15
    const int t = r >> 5, rr = r & 31;
    half8* base = af + ((size_t)bb * CH_TILES_TOTAL + t) * 64;
    base[rr]      = k0;   // lanes 0..31 (k-half 0)
    base[32 + rr] = k1;   // lanes 32..63 (k-half 1)
}

__global__ __launch_bounds__(CH_BLOCK, 4) void chamfer_mfma(
    const float* __restrict__ src, const float* __restrict__ trg,
    const half8* __restrict__ af,
    unsigned int* __restrict__ out_all)
{
    const int tid  = threadIdx.x;
    const int lane = tid & 63;
    const int wave = tid >> 6;
    const int l31  = lane & 31;
    const int lhi  = lane >> 5;

    const int bz  = blockIdx.z;          // dir*16 + b
    const int b   = bz & (CH_B - 1);
    const int dir = bz >> 4;             // 0: rows=src, cols=trg ; 1: swapped
    const float* Q = dir ? src : trg;
    unsigned int* out = out_all + ((size_t)dir * CH_B + b) * CH_N;
    const float* Qb = Q + (size_t)b * CH_N * 3;

    // ---- B fragments: 2 sets of 32 cols each (64 cols per wave) ----
    half8 bfrag[2];
    float qn[2];
    const int col0 = blockIdx.x * CH_QT + wave * 64 + l31;
    #pragma unroll
    for (int s = 0; s < 2; ++s) {
        const int col = col0 + s * 32;
        const float qx = Qb[col * 3 + 0], qy = Qb[col * 3 + 1], qz = Qb[col * 3 + 2];
        qn[s] = qx * qx + qy * qy + qz * qz;
        const _Float16 xh = (_Float16)qx, yh = (_Float16)qy, zh = (_Float16)qz;
        const _Float16 xl = (_Float16)(qx - (float)xh);
        const _Float16 yl = (_Float16)(qy - (float)yh);
        const _Float16 zl = (_Float16)(qz - (float)zh);
        half8 f;
        if (lhi == 0) {      // k = 0..7
            f[0] = (_Float16)1.0f; f[1] = (_Float16)1.0f;
            f[2] = xh; f[3] = yh; f[4] = zh;
            f[5] = xh; f[6] = yh; f[7] = zh;
        } else {             // k = 8..15
            f[0] = xl; f[1] = yl; f[2] = zl;
            f[3] = (_Float16)0.0f; f[4] = (_Float16)0.0f;
            f[5] = (_Float16)0.0f; f[6] = (_Float16)0.0f; f[7] = (_Float16)0.0f;
        }
        bfrag[s] = f;
    }

    const half8* afb = af + ((size_t)bz * CH_TILES_TOTAL
                             + (size_t)blockIdx.y * CH_TILES_BLK) * 64;

    const floatx16 zero = {0.f,0.f,0.f,0.f,0.f,0.f,0.f,0.f,
                           0.f,0.f,0.f,0.f,0.f,0.f,0.f,0.f};
    float m0 = __builtin_inff(), m1 = __builtin_inff();

    #pragma unroll 2
    for (int t = 0; t < CH_TILES_BLK; ++t) {
        const half8 a = afb[t * 64 + lane];  // all 4 waves: same addr -> L1 hit
        floatx16 d0 = __builtin_amdgcn_mfma_f32_32x32x16_f16(a, bfrag[0], zero, 0, 0, 0);
        floatx16 d1 = __builtin_amdgcn_mfma_f32_32x32x16_f16(a, bfrag[1], zero, 0, 0, 0);
        // min3-shaped reduction: 8x v_min3 + 1x v_min per 16 values
        {
            const float u0 = fminf(fminf(d0[0],  d0[1]),  d0[2]);
            const float u1 = fminf(fminf(d0[3],  d0[4]),  d0[5]);
            const float u2 = fminf(fminf(d0[6],  d0[7]),  d0[8]);
            const float u3 = fminf(fminf(d0[9],  d0[10]), d0[11]);
            const float u4 = fminf(fminf(d0[12], d0[13]), d0[14]);
            const float v  = fminf(fminf(u0, u1), u2);
            const float w  = fminf(fminf(u3, u4), d0[15]);
            m0 = fminf(fminf(m0, v), w);
        }
        {
            const float u0 = fminf(fminf(d1[0],  d1[1]),  d1[2]);
            const float u1 = fminf(fminf(d1[3],  d1[4]),  d1[5]);
            const float u2 = fminf(fminf(d1[6],  d1[7]),  d1[8]);
            const float u3 = fminf(fminf(d1[9],  d1[10]), d1[11]);
            const float u4 = fminf(fminf(d1[12], d1[13]), d1[14]);
            const float v  = fminf(fminf(u0, u1), u2);
            const float w  = fminf(fminf(u3, u4), d1[15]);
            m1 = fminf(fminf(m1, v), w);
        }
    }

    // epilogue: add ||q||^2, clamp >=0, combine row-halves, global atomicMin
    float v0 = fmaxf(m0 + qn[0], 0.0f);
    float v1 = fmaxf(m1 + qn[1], 0.0f);
    v0 = fminf(v0, __shfl_xor(v0, 32));
    v1 = fminf(v1, __shfl_xor(v1, 32));
    if (lane < 32) {
        atomicMin(&out[col0],      __float_as_uint(v0));
        atomicMin(&out[col0 + 32], __float_as_uint(v1));
    }
}

extern "C" void kernel_launch(void* const* d_in, const int* in_sizes, int n_in,
                              void* d_out, int out_size, void* d_ws, size_t ws_size,
                              hipStream_t stream) {
    const float* src = (const float*)d_in[0];
    const float* trg = (const float*)d_in[1];
    unsigned int* out = (unsigned int*)d_out;
    half8* af = (half8*)d_ws;   // 2*16*128*64 half8 = 4 MB

    // Init outputs to 0x7f7f7f7f (~3.4e38): valid +inf under uint-ordered min
    // for nonnegative values.
    hipMemsetAsync(out, 0x7f, (size_t)2 * CH_B * CH_N * sizeof(float), stream);

    build_afrag<<<dim3(2 * CH_B * CH_N / CH_BLOCK), dim3(CH_BLOCK), 0, stream>>>(src, trg, af);

    dim3 grid(CH_NQT, CH_PSPLIT, 2 * CH_B);
    chamfer_mfma<<<grid, dim3(CH_BLOCK), 0, stream>>>(src, trg, af, out);
}

// Round 5
// 29.019 us; speedup vs baseline: 2.0847x; 1.2055x over previous
//
#include <hip/hip_runtime.h>
#include <hip/hip_bf16.h>

// Chamfer loss via MFMA, B=16, N=4096, D=3, fp32 in/out.
// d2[p][q] = ||p||^2 + ||q||^2 - 2 p.q as a 32x32x16 f16 MFMA tile with
// hi/lo f16 split (error ~1e-3; ||q||^2 added per-column after the min).
// A-fragments precomputed into d_ws by build_afrag (which also inits the
// output to +big for the uint atomicMin combine). Main kernel: no LDS, no
// barriers, 4-deep register prefetch of A-frags.

typedef _Float16 half8    __attribute__((ext_vector_type(8)));
typedef float    floatx16 __attribute__((ext_vector_type(16)));

#define CH_B 16
#define CH_N 4096
#define CH_BLOCK 256
#define CH_QT 256                          // q-cols per block (64/wave)
#define CH_NQT (CH_N / CH_QT)              // 16
#define CH_PSPLIT 2
#define CH_TILES_TOTAL (CH_N / 32)         // 128 row-tiles per (dir,b)
#define CH_TILES_BLK (CH_TILES_TOTAL / CH_PSPLIT)  // 64 per block
#define CH_PF 4                            // prefetch depth (tiles)

// One thread per point (dir,b,r): build the K=16 hi/lo A-fragment.
// Also initializes out[gid] (131072 threads == 2*B*N out elements).
__global__ __launch_bounds__(CH_BLOCK) void build_afrag(
    const float* __restrict__ src, const float* __restrict__ trg,
    half8* __restrict__ af, unsigned int* __restrict__ out_init)
{
    const int gid = blockIdx.x * CH_BLOCK + threadIdx.x;  // 0 .. 2*16*4096
    out_init[gid] = 0x7f7f7f7fu;   // ~3.4e38: +inf under uint-min for >=0 vals

    const int r   = gid & (CH_N - 1);
    const int bb  = gid >> 12;            // dir*16 + b
    const int dir = bb >> 4;
    const float* P = dir ? trg : src;
    const float* p = P + ((size_t)(bb & 15) * CH_N + r) * 3;
    const float px = p[0], py = p[1], pz = p[2];
    const float ax = -2.0f * px, ay = -2.0f * py, az = -2.0f * pz;
    const float pn = px * px + py * py + pz * pz;
    const _Float16 axh = (_Float16)ax, ayh = (_Float16)ay, azh = (_Float16)az;
    const _Float16 axl = (_Float16)(ax - (float)axh);
    const _Float16 ayl = (_Float16)(ay - (float)ayh);
    const _Float16 azl = (_Float16)(az - (float)azh);
    const _Float16 pnh = (_Float16)pn, pnl = (_Float16)(pn - (float)pnh);
    const _Float16 z0 = (_Float16)0.0f;
    half8 k0 = {pnh, pnl, axh, ayh, azh, axl, ayl, azl};  // k 0..7
    half8 k1 = {axh, ayh, azh, z0, z0, z0, z0, z0};       // k 8..15
    const int t = r >> 5, rr = r & 31;
    half8* base = af + ((size_t)bb * CH_TILES_TOTAL + t) * 64;
    base[rr]      = k0;   // lanes 0..31 (k-half 0)
    base[32 + rr] = k1;   // lanes 32..63 (k-half 1)
}

__global__ __launch_bounds__(CH_BLOCK, 4) void chamfer_mfma(
    const float* __restrict__ src, const float* __restrict__ trg,
    const half8* __restrict__ af,
    unsigned int* __restrict__ out_all)
{
    const int tid  = threadIdx.x;
    const int lane = tid & 63;
    const int wave = tid >> 6;
    const int l31  = lane & 31;
    const int lhi  = lane >> 5;

    const int bz  = blockIdx.z;          // dir*16 + b
    const int b   = bz & (CH_B - 1);
    const int dir = bz >> 4;             // 0: rows=src, cols=trg ; 1: swapped
    const float* Q = dir ? src : trg;
    unsigned int* out = out_all + ((size_t)dir * CH_B + b) * CH_N;
    const float* Qb = Q + (size_t)b * CH_N * 3;

    // ---- B fragments: 2 sets of 32 cols each (64 cols per wave) ----
    half8 bfrag[2];
    float qn[2];
    const int col0 = blockIdx.x * CH_QT + wave * 64 + l31;
    #pragma unroll
    for (int s = 0; s < 2; ++s) {
        const int col = col0 + s * 32;
        const float qx = Qb[col * 3 + 0], qy = Qb[col * 3 + 1], qz = Qb[col * 3 + 2];
        qn[s] = qx * qx + qy * qy + qz * qz;
        const _Float16 xh = (_Float16)qx, yh = (_Float16)qy, zh = (_Float16)qz;
        const _Float16 xl = (_Float16)(qx - (float)xh);
        const _Float16 yl = (_Float16)(qy - (float)yh);
        const _Float16 zl = (_Float16)(qz - (float)zh);
        half8 f;
        if (lhi == 0) {      // k = 0..7
            f[0] = (_Float16)1.0f; f[1] = (_Float16)1.0f;
            f[2] = xh; f[3] = yh; f[4] = zh;
            f[5] = xh; f[6] = yh; f[7] = zh;
        } else {             // k = 8..15
            f[0] = xl; f[1] = yl; f[2] = zl;
            f[3] = (_Float16)0.0f; f[4] = (_Float16)0.0f;
            f[5] = (_Float16)0.0f; f[6] = (_Float16)0.0f; f[7] = (_Float16)0.0f;
        }
        bfrag[s] = f;
    }

    const half8* afb = af + ((size_t)bz * CH_TILES_TOTAL
                             + (size_t)blockIdx.y * CH_TILES_BLK) * 64;

    const floatx16 zero = {0.f,0.f,0.f,0.f,0.f,0.f,0.f,0.f,
                           0.f,0.f,0.f,0.f,0.f,0.f,0.f,0.f};
    float m0 = __builtin_inff(), m1 = __builtin_inff();

    // 4-deep register prefetch pipeline over the 64 row-tiles.
    half8 pf[CH_PF];
    #pragma unroll
    for (int k = 0; k < CH_PF; ++k) pf[k] = afb[k * 64 + lane];

    #pragma unroll 1
    for (int t = 0; t < CH_TILES_BLK; t += CH_PF) {
        half8 cur[CH_PF];
        #pragma unroll
        for (int k = 0; k < CH_PF; ++k) cur[k] = pf[k];
        if (t + CH_PF < CH_TILES_BLK) {
            #pragma unroll
            for (int k = 0; k < CH_PF; ++k)
                pf[k] = afb[(t + CH_PF + k) * 64 + lane];  // next window in flight
        }
        #pragma unroll
        for (int k = 0; k < CH_PF; ++k) {
            const half8 a = cur[k];
            floatx16 d0 = __builtin_amdgcn_mfma_f32_32x32x16_f16(a, bfrag[0], zero, 0, 0, 0);
            floatx16 d1 = __builtin_amdgcn_mfma_f32_32x32x16_f16(a, bfrag[1], zero, 0, 0, 0);
            {   // min3-shaped reduction: ~8 instrs per 16 values
                const float u0 = fminf(fminf(d0[0],  d0[1]),  d0[2]);
                const float u1 = fminf(fminf(d0[3],  d0[4]),  d0[5]);
                const float u2 = fminf(fminf(d0[6],  d0[7]),  d0[8]);
                const float u3 = fminf(fminf(d0[9],  d0[10]), d0[11]);
                const float u4 = fminf(fminf(d0[12], d0[13]), d0[14]);
                const float v  = fminf(fminf(u0, u1), u2);
                const float w  = fminf(fminf(u3, u4), d0[15]);
                m0 = fminf(fminf(m0, v), w);
            }
            {
                const float u0 = fminf(fminf(d1[0],  d1[1]),  d1[2]);
                const float u1 = fminf(fminf(d1[3],  d1[4]),  d1[5]);
                const float u2 = fminf(fminf(d1[6],  d1[7]),  d1[8]);
                const float u3 = fminf(fminf(d1[9],  d1[10]), d1[11]);
                const float u4 = fminf(fminf(d1[12], d1[13]), d1[14]);
                const float v  = fminf(fminf(u0, u1), u2);
                const float w  = fminf(fminf(u3, u4), d1[15]);
                m1 = fminf(fminf(m1, v), w);
            }
        }
    }

    // epilogue: add ||q||^2, clamp >=0, combine row-halves, global atomicMin
    float v0 = fmaxf(m0 + qn[0], 0.0f);
    float v1 = fmaxf(m1 + qn[1], 0.0f);
    v0 = fminf(v0, __shfl_xor(v0, 32));
    v1 = fminf(v1, __shfl_xor(v1, 32));
    if (lane < 32) {
        atomicMin(&out[col0],      __float_as_uint(v0));
        atomicMin(&out[col0 + 32], __float_as_uint(v1));
    }
}

extern "C" void kernel_launch(void* const* d_in, const int* in_sizes, int n_in,
                              void* d_out, int out_size, void* d_ws, size_t ws_size,
                              hipStream_t stream) {
    const float* src = (const float*)d_in[0];
    const float* trg = (const float*)d_in[1];
    unsigned int* out = (unsigned int*)d_out;
    half8* af = (half8*)d_ws;   // 2*16*128*64 half8 = 4 MB

    // build_afrag also initializes out (131072 threads == out elements).
    build_afrag<<<dim3(2 * CH_B * CH_N / CH_BLOCK), dim3(CH_BLOCK), 0, stream>>>(
        src, trg, af, out);

    dim3 grid(CH_NQT, CH_PSPLIT, 2 * CH_B);
    chamfer_mfma<<<grid, dim3(CH_BLOCK), 0, stream>>>(src, trg, af, out);
}

// Round 6
// 27.427 us; speedup vs baseline: 2.2057x; 1.0581x over previous
//
#include <hip/hip_runtime.h>
#include <hip/hip_bf16.h>

// Chamfer loss via MFMA, B=16, N=4096, D=3, fp32 in/out.
// d2[p][q] = ||p||^2 + ||q||^2 - 2 p.q as a 32x32x16 f16 MFMA tile with
// hi/lo f16 split (error ~1e-3; ||q||^2 added per-column after the min).
// A-fragments precomputed into d_ws by build_afrag (which also inits the
// output to +big for the uint atomicMin combine). Main kernel: no LDS, no
// barriers, 4-deep register prefetch, XCD-aware work mapping so the 16
// blocks sharing one A-slice land on one XCD (L2 reuse).

typedef _Float16 half8    __attribute__((ext_vector_type(8)));
typedef float    floatx16 __attribute__((ext_vector_type(16)));

#define CH_B 16
#define CH_N 4096
#define CH_BLOCK 256
#define CH_QT 256                          // q-cols per block (64/wave)
#define CH_NQT (CH_N / CH_QT)              // 16
#define CH_PSPLIT 2
#define CH_TILES_TOTAL (CH_N / 32)         // 128 row-tiles per (dir,b)
#define CH_TILES_BLK (CH_TILES_TOTAL / CH_PSPLIT)  // 64 per block
#define CH_PF 4                            // prefetch depth (tiles)
#define CH_NSLICE (2 * CH_B * CH_PSPLIT)   // 64 A-slices
#define CH_NBLK (CH_NSLICE * CH_NQT)       // 1024 blocks

// One thread per point (dir,b,r): build the K=16 hi/lo A-fragment.
// Also initializes out[gid] (131072 threads == 2*B*N out elements).
__global__ __launch_bounds__(CH_BLOCK) void build_afrag(
    const float* __restrict__ src, const float* __restrict__ trg,
    half8* __restrict__ af, unsigned int* __restrict__ out_init)
{
    const int gid = blockIdx.x * CH_BLOCK + threadIdx.x;  // 0 .. 2*16*4096
    out_init[gid] = 0x7f7f7f7fu;   // ~3.4e38: +inf under uint-min for >=0 vals

    const int r   = gid & (CH_N - 1);
    const int bb  = gid >> 12;            // dir*16 + b
    const int dir = bb >> 4;
    const float* P = dir ? trg : src;
    const float* p = P + ((size_t)(bb & 15) * CH_N + r) * 3;
    const float px = p[0], py = p[1], pz = p[2];
    const float ax = -2.0f * px, ay = -2.0f * py, az = -2.0f * pz;
    const float pn = px * px + py * py + pz * pz;
    const _Float16 axh = (_Float16)ax, ayh = (_Float16)ay, azh = (_Float16)az;
    const _Float16 axl = (_Float16)(ax - (float)axh);
    const _Float16 ayl = (_Float16)(ay - (float)ayh);
    const _Float16 azl = (_Float16)(az - (float)azh);
    const _Float16 pnh = (_Float16)pn, pnl = (_Float16)(pn - (float)pnh);
    const _Float16 z0 = (_Float16)0.0f;
    half8 k0 = {pnh, pnl, axh, ayh, azh, axl, ayl, azl};  // k 0..7
    half8 k1 = {axh, ayh, azh, z0, z0, z0, z0, z0};       // k 8..15
    const int t = r >> 5, rr = r & 31;
    half8* base = af + ((size_t)bb * CH_TILES_TOTAL + t) * 64;
    base[rr]      = k0;   // lanes 0..31 (k-half 0)
    base[32 + rr] = k1;   // lanes 32..63 (k-half 1)
}

__global__ __launch_bounds__(CH_BLOCK, 4) void chamfer_mfma(
    const float* __restrict__ src, const float* __restrict__ trg,
    const half8* __restrict__ af,
    unsigned int* __restrict__ out_all)
{
    const int tid  = threadIdx.x;
    const int lane = tid & 63;
    const int wave = tid >> 6;
    const int l31  = lane & 31;
    const int lhi  = lane >> 5;

    // XCD-aware mapping: blocks with the same A-slice have linear ids that
    // differ by multiples of 64 -> same (id % 8) -> same XCD -> L2 reuse.
    const int L     = blockIdx.x;     // 0..1023
    const int qt    = L >> 6;         // 0..15  (q-tile)
    const int slice = L & 63;         // (dir,b,psl)
    const int psl   = slice & 1;
    const int bz    = slice >> 1;     // dir*16 + b
    const int b     = bz & (CH_B - 1);
    const int dir   = bz >> 4;        // 0: rows=src, cols=trg ; 1: swapped

    const float* Q = dir ? src : trg;
    unsigned int* out = out_all + ((size_t)dir * CH_B + b) * CH_N;
    const float* Qb = Q + (size_t)b * CH_N * 3;

    // ---- B fragments: 2 sets of 32 cols each (64 cols per wave) ----
    half8 bfrag[2];
    float qn[2];
    const int col0 = qt * CH_QT + wave * 64 + l31;
    #pragma unroll
    for (int s = 0; s < 2; ++s) {
        const int col = col0 + s * 32;
        const float qx = Qb[col * 3 + 0], qy = Qb[col * 3 + 1], qz = Qb[col * 3 + 2];
        qn[s] = qx * qx + qy * qy + qz * qz;
        const _Float16 xh = (_Float16)qx, yh = (_Float16)qy, zh = (_Float16)qz;
        const _Float16 xl = (_Float16)(qx - (float)xh);
        const _Float16 yl = (_Float16)(qy - (float)yh);
        const _Float16 zl = (_Float16)(qz - (float)zh);
        half8 f;
        if (lhi == 0) {      // k = 0..7
            f[0] = (_Float16)1.0f; f[1] = (_Float16)1.0f;
            f[2] = xh; f[3] = yh; f[4] = zh;
            f[5] = xh; f[6] = yh; f[7] = zh;
        } else {             // k = 8..15
            f[0] = xl; f[1] = yl; f[2] = zl;
            f[3] = (_Float16)0.0f; f[4] = (_Float16)0.0f;
            f[5] = (_Float16)0.0f; f[6] = (_Float16)0.0f; f[7] = (_Float16)0.0f;
        }
        bfrag[s] = f;
    }

    const half8* afb = af + ((size_t)bz * CH_TILES_TOTAL
                             + (size_t)psl * CH_TILES_BLK) * 64;

    float m0 = __builtin_inff(), m1 = __builtin_inff();
    const floatx16 zero = {0.f,0.f,0.f,0.f,0.f,0.f,0.f,0.f,
                           0.f,0.f,0.f,0.f,0.f,0.f,0.f,0.f};

    // 4-deep register prefetch pipeline over the 64 row-tiles.
    half8 pf[CH_PF];
    #pragma unroll
    for (int k = 0; k < CH_PF; ++k) pf[k] = afb[k * 64 + lane];

    #pragma unroll 1
    for (int t = 0; t < CH_TILES_BLK; t += CH_PF) {
        half8 cur[CH_PF];
        #pragma unroll
        for (int k = 0; k < CH_PF; ++k) cur[k] = pf[k];
        if (t + CH_PF < CH_TILES_BLK) {
            #pragma unroll
            for (int k = 0; k < CH_PF; ++k)
                pf[k] = afb[(t + CH_PF + k) * 64 + lane];  // next window in flight
        }
        #pragma unroll
        for (int k = 0; k < CH_PF; ++k) {
            const half8 a = cur[k];
            floatx16 d0 = __builtin_amdgcn_mfma_f32_32x32x16_f16(a, bfrag[0], zero, 0, 0, 0);
            floatx16 d1 = __builtin_amdgcn_mfma_f32_32x32x16_f16(a, bfrag[1], zero, 0, 0, 0);
            {   // min3-shaped reduction: ~8 instrs per 16 values
                const float u0 = fminf(fminf(d0[0],  d0[1]),  d0[2]);
                const float u1 = fminf(fminf(d0[3],  d0[4]),  d0[5]);
                const float u2 = fminf(fminf(d0[6],  d0[7]),  d0[8]);
                const float u3 = fminf(fminf(d0[9],  d0[10]), d0[11]);
                const float u4 = fminf(fminf(d0[12], d0[13]), d0[14]);
                const float v  = fminf(fminf(u0, u1), u2);
                const float w  = fminf(fminf(u3, u4), d0[15]);
                m0 = fminf(fminf(m0, v), w);
            }
            {
                const float u0 = fminf(fminf(d1[0],  d1[1]),  d1[2]);
                const float u1 = fminf(fminf(d1[3],  d1[4]),  d1[5]);
                const float u2 = fminf(fminf(d1[6],  d1[7]),  d1[8]);
                const float u3 = fminf(fminf(d1[9],  d1[10]), d1[11]);
                const float u4 = fminf(fminf(d1[12], d1[13]), d1[14]);
                const float v  = fminf(fminf(u0, u1), u2);
                const float w  = fminf(fminf(u3, u4), d1[15]);
                m1 = fminf(fminf(m1, v), w);
            }
        }
    }

    // epilogue: add ||q||^2, clamp >=0, combine row-halves, global atomicMin
    float v0 = fmaxf(m0 + qn[0], 0.0f);
    float v1 = fmaxf(m1 + qn[1], 0.0f);
    v0 = fminf(v0, __shfl_xor(v0, 32));
    v1 = fminf(v1, __shfl_xor(v1, 32));
    if (lane < 32) {
        atomicMin(&out[col0],      __float_as_uint(v0));
        atomicMin(&out[col0 + 32], __float_as_uint(v1));
    }
}

extern "C" void kernel_launch(void* const* d_in, const int* in_sizes, int n_in,
                              void* d_out, int out_size, void* d_ws, size_t ws_size,
                              hipStream_t stream) {
    const float* src = (const float*)d_in[0];
    const float* trg = (const float*)d_in[1];
    unsigned int* out = (unsigned int*)d_out;
    half8* af = (half8*)d_ws;   // 2*16*128*64 half8 = 4 MB

    // build_afrag also initializes out (131072 threads == out elements).
    build_afrag<<<dim3(2 * CH_B * CH_N / CH_BLOCK), dim3(CH_BLOCK), 0, stream>>>(
        src, trg, af, out);

    chamfer_mfma<<<dim3(CH_NBLK), dim3(CH_BLOCK), 0, stream>>>(src, trg, af, out);
}